// Round 11
// baseline (291.134 us; speedup 1.0000x reference)
//
#include <hip/hip_runtime.h>
#include <hip/hip_bf16.h>
#include <math.h>

#define NROWS 8192
#define DDIM  4096
#define NEXP  64
#define KSPLIT 8                 // K split ACROSS blocks (kh); waves split it further
#define KCHUNK (DDIM / KSPLIT)   // 512 per block; 128 per wave
#define KSTEPS 4                 // per-wave k32 steps (128/32)

typedef __attribute__((ext_vector_type(8))) short bf16x8;
typedef __attribute__((ext_vector_type(4))) float f32x4;

__device__ inline unsigned short bf16_rne(float f) {
    unsigned u = __builtin_bit_cast(unsigned, f);
    u += 0x7FFF + ((u >> 16) & 1);
    return (unsigned short)(u >> 16);
}

// split 8 fp32 -> hi/lo bf16 (x = hi + lo + r, |r| <= 2^-18|x|)
__device__ inline void split8(const float* xf, bf16x8& hi, bf16x8& lo) {
#pragma unroll
    for (int j = 0; j < 8; j++) {
        const unsigned short h = bf16_rne(xf[j]);
        const float hf = __builtin_bit_cast(float, (unsigned)h << 16);
        hi[j] = (short)h;
        lo[j] = (short)bf16_rne(xf[j] - hf);
    }
}

// Preconvert W (64 x 4096 fp32) into MFMA B-fragment-linear bf16 hi/lo:
// frag elem j of lane l, tile t, k-chunk kc = B[k=kc*32+(l>>4)*8+j][n=t*16+(l&15)]
// at ((kc*4+t)*64+l)*8. ~1 MB total -> L2/L3-resident for the GEMM.
__global__ __launch_bounds__(256) void wfrag_kernel(
    const float* __restrict__ w, unsigned short* __restrict__ whi,
    unsigned short* __restrict__ wlo)
{
    const int kc = blockIdx.x;            // 0..127
    const int t  = threadIdx.x >> 6;      // n-tile 0..3
    const int l  = threadIdx.x & 63;
    const int e  = t * 16 + (l & 15);
    const int k0 = kc * 32 + ((l >> 4) * 8);
    const float* p = w + (size_t)e * DDIM + k0;
    float xf[8];
    *(float4*)&xf[0] = *(const float4*)p;
    *(float4*)&xf[4] = *(const float4*)(p + 4);
    bf16x8 hi, lo;
    split8(xf, hi, lo);
    const size_t off = ((size_t)(kc * 4 + t) * 64 + l) * 8;
    *(bf16x8*)(whi + off) = hi;
    *(bf16x8*)(wlo + off) = lo;
}

// Shared GEMM body (production + diagnostic probe use the SAME inlined code,
// so probe counters describe production codegen). Verified R8/R10 structure:
// block = 4 waves on the same 32 rows; wave wv covers k-range
// kh*KCHUNK + wv*128. Double-buffered wave-private LDS staging via
// global_load_lds w=16, pre-swizzled source (slot ^= row&7, rule 21),
// counted s_waitcnt vmcnt(8) + sched_barrier pins. Atomic-free tail:
// vmcnt(0) drain, wave partials to LDS, one __syncthreads, 4-way sum,
// coalesced dwordx4 stores to part[kh].
__device__ __forceinline__ void gemm_body(
    const float* __restrict__ x, const unsigned short* __restrict__ whi,
    const unsigned short* __restrict__ wlo, float* __restrict__ part,
    float* ldsx, int bx, int kh)
{
    const int tid = threadIdx.x;
    const int wv  = tid >> 6;
    const int l   = tid & 63;
    const int q   = l >> 4;
    const int col = l & 15;
    const int c7  = col & 7;
    const int r0  = bx * 32;               // 32 rows per block
    const int kb  = kh * KCHUNK + wv * 128;  // this wave's private 128-k range

    const int slr   = l >> 3;
    const int slotp = l & 7;

    float* ldsw = ldsx + wv * 2048;        // this wave's two 1024-float bufs

    const unsigned short* bhp = whi + ((size_t)(kb / 32) * 4 * 64 + l) * 8;
    const unsigned short* blp = wlo + ((size_t)(kb / 32) * 4 * 64 + l) * 8;

    f32x4 acc[2][4];
#pragma unroll
    for (int m = 0; m < 2; m++)
#pragma unroll
        for (int t = 0; t < 4; t++) acc[m][t] = f32x4{0, 0, 0, 0};

    auto STAGE = [&](int buf, int s) {     // 4 x global_load_lds dwordx4
#pragma unroll
        for (int g = 0; g < 4; g++) {
            const int lr   = g * 8 + slr;
            const int slot = slotp ^ (lr & 7);
            const float* gp = x + (size_t)(r0 + lr) * DDIM + kb + s * 32 + slot * 4;
            __builtin_amdgcn_global_load_lds(
                (const __attribute__((address_space(1))) void*)gp,
                (__attribute__((address_space(3))) void*)(ldsw + buf * 1024 + g * 256),
                16, 0, 0);
        }
    };

    STAGE(0, 0);
    __builtin_amdgcn_sched_barrier(0);     // pin stage block (wait-count integrity)

#pragma unroll
    for (int s = 0; s < KSTEPS; s++) {
        const int buf = s & 1;

        // B loads for this step (exactly 8 dwordx4, L2-resident)
        bf16x8 bh[4], bl[4];
        const unsigned short* bhs = bhp + (size_t)s * 4 * 64 * 8;
        const unsigned short* bls = blp + (size_t)s * 4 * 64 * 8;
#pragma unroll
        for (int t = 0; t < 4; t++) {
            bh[t] = *(const bf16x8*)(bhs + (size_t)t * 64 * 8);
            bl[t] = *(const bf16x8*)(bls + (size_t)t * 64 * 8);
        }

        // exactly 8 B-loads issued since stage(buf) -> vmcnt(8) retires the
        // stage (in-order), keeps the B-loads in flight.
        asm volatile("s_waitcnt vmcnt(8)" ::: "memory");
        __builtin_amdgcn_sched_barrier(0); // nothing crosses the wait (rule #18)

        // read this wave's fragments from LDS (swizzled, bank-uniform b128)
        float xr[2][8];
#pragma unroll
        for (int m = 0; m < 2; m++) {
            const float* rbp = ldsw + buf * 1024 + (m * 16 + col) * 32;
            const int sp0 = (q * 2) ^ c7;
            *(float4*)&xr[m][0] = *(const float4*)(rbp + sp0 * 4);
            *(float4*)&xr[m][4] = *(const float4*)(rbp + (sp0 ^ 1) * 4);
        }

        // prefetch next step (skipped on last iter -- compile-time)
        if (s + 1 < KSTEPS) STAGE(buf ^ 1, s + 1);
        __builtin_amdgcn_sched_barrier(0);

        bf16x8 ah[2], al[2];
        split8(xr[0], ah[0], al[0]);
        split8(xr[1], ah[1], al[1]);
#pragma unroll
        for (int m = 0; m < 2; m++)
#pragma unroll
            for (int t = 0; t < 4; t++) {
                acc[m][t] = __builtin_amdgcn_mfma_f32_16x16x32_bf16(ah[m], bh[t], acc[m][t], 0, 0, 0);
                acc[m][t] = __builtin_amdgcn_mfma_f32_16x16x32_bf16(ah[m], bl[t], acc[m][t], 0, 0, 0);
                acc[m][t] = __builtin_amdgcn_mfma_f32_16x16x32_bf16(al[m], bh[t], acc[m][t], 0, 0, 0);
            }
    }

    // ---- atomic-free tail: cross-wave K reduction in LDS ----
    asm volatile("s_waitcnt vmcnt(0)" ::: "memory");   // all LDS-DMA landed (alias safety)
    __builtin_amdgcn_sched_barrier(0);

    // C/D: row_local = m*16 + q*4 + r, exp = t*16 + col (m89-verified mapping)
#pragma unroll
    for (int m = 0; m < 2; m++)
#pragma unroll
        for (int t = 0; t < 4; t++)
#pragma unroll
            for (int r = 0; r < 4; r++)
                ldsx[wv * 2048 + (m * 16 + q * 4 + r) * 64 + t * 16 + col] = acc[m][t][r];

    __syncthreads();

    // 256 threads x 8 values: sum the 4 wave-partials, store coalesced.
    const f32x4* lp = (const f32x4*)ldsx;   // wave region stride = 512 f32x4
    const f32x4 s0 = lp[tid * 2]     + lp[512 + tid * 2]     + lp[1024 + tid * 2]     + lp[1536 + tid * 2];
    const f32x4 s1 = lp[tid * 2 + 1] + lp[512 + tid * 2 + 1] + lp[1024 + tid * 2 + 1] + lp[1536 + tid * 2 + 1];
    float* po = part + (size_t)kh * NROWS * NEXP + (size_t)r0 * NEXP + tid * 8;
    *(f32x4*)po       = s0;
    *(f32x4*)(po + 4) = s1;
}

__global__ __launch_bounds__(256) void gemm_partial_kernel(
    const float* __restrict__ x, const unsigned short* __restrict__ whi,
    const unsigned short* __restrict__ wlo, float* __restrict__ part)
{
    __shared__ float ldsx[4 * 2 * 1024];   // 32 KB staging; aliased for reduce
    gemm_body(x, whi, wlo, part, ldsx, blockIdx.x, blockIdx.y);
}

// ---- DIAGNOSTIC PROBE (R11): 3x the identical GEMM body into scratch ----
// Purpose: at ~115 us this dispatch outranks the 77 us poison fills and
// enters rocprof's top-5 WITH COUNTERS -- first direct view of Occupancy/
// VALUBusy/MfmaUtil/FETCH/VGPR for the GEMM after 10 blind rounds. The
// __syncthreads inside the body (reached uniformly 3x) separates reps.
__global__ __launch_bounds__(256) void gemm_probe_kernel(
    const float* __restrict__ x, const unsigned short* __restrict__ whi,
    const unsigned short* __restrict__ wlo, float* __restrict__ part2)
{
    __shared__ float ldsx[4 * 2 * 1024];
    gemm_body(x, whi, wlo, part2, ldsx, blockIdx.x, blockIdx.y);
    __syncthreads();
    gemm_body(x, whi, wlo, part2, ldsx, blockIdx.x, blockIdx.y);
    __syncthreads();
    gemm_body(x, whi, wlo, part2, ldsx, blockIdx.x, blockIdx.y);
}

// One wave per row: sum 8 split-K partials, sigmoid, +bias, top-2 (tie ->
// lower index), normalize. Kernel boundary provides cross-XCD visibility of
// part (plain stores -> plain loads, verified pattern R0/R8/R10).
// out: [weights 2N][indices-as-float 2N][scores 64N]
__global__ __launch_bounds__(256) void gate_topk_kernel(
    const float* __restrict__ part, const float* __restrict__ bias,
    float* __restrict__ out)
{
    const int tid = threadIdx.x;
    const int e   = tid & 63;
    const int row = blockIdx.x * 4 + (tid >> 6);
    const size_t idx = (size_t)row * NEXP + e;

    const float be = bias[e];           // issue before partial loads
    float logit = 0.f;
#pragma unroll
    for (int s = 0; s < KSPLIT; s++)
        logit += part[(size_t)s * NROWS * NEXP + idx];
    const float score = 1.0f / (1.0f + expf(-logit));
    out[(size_t)4 * NROWS + idx] = score;           // scores

    const float biased = score + be;

    float v = biased; int bi = e;
#pragma unroll
    for (int off = 32; off; off >>= 1) {
        const float ov = __shfl_xor(v, off);
        const int   oi = __shfl_xor(bi, off);
        if (ov > v || (ov == v && oi < bi)) { v = ov; bi = oi; }
    }
    const int i1 = bi;

    float v2 = (e == i1) ? -INFINITY : biased;
    int bi2 = e;
#pragma unroll
    for (int off = 32; off; off >>= 1) {
        const float ov = __shfl_xor(v2, off);
        const int   oi = __shfl_xor(bi2, off);
        if (ov > v2 || (ov == v2 && oi < bi2)) { v2 = ov; bi2 = oi; }
    }
    const int i2 = bi2;

    const float s1 = __shfl(score, i1);
    const float s2 = __shfl(score, i2);
    if (e == 0) {
        const float inv = 1.0f / (s1 + s2);
        out[(size_t)row * 2 + 0] = s1 * inv;
        out[(size_t)row * 2 + 1] = s2 * inv;
        out[(size_t)2 * NROWS + row * 2 + 0] = (float)i1;
        out[(size_t)2 * NROWS + row * 2 + 1] = (float)i2;
    }
}

extern "C" void kernel_launch(void* const* d_in, const int* in_sizes, int n_in,
                              void* d_out, int out_size, void* d_ws, size_t ws_size,
                              hipStream_t stream)
{
    const float* x    = (const float*)d_in[0];
    const float* w    = (const float*)d_in[1];
    const float* bias = (const float*)d_in[2];
    float* out  = (float*)d_out;

    float* part = (float*)d_ws;                                 // 8 x 2 MB
    const size_t part_bytes = (size_t)KSPLIT * NROWS * NEXP * 4;
    unsigned short* whi = (unsigned short*)((char*)d_ws + part_bytes);  // 512 KB
    unsigned short* wlo = whi + (size_t)NEXP * DDIM;                    // 512 KB
    float* part2 = (float*)(wlo + (size_t)NEXP * DDIM);         // 16 MB scratch (probe)

    wfrag_kernel<<<DDIM / 32, 256, 0, stream>>>(w, whi, wlo);
    dim3 g1(NROWS / 32, KSPLIT);                                // (256, 8) = 2048 blocks
    gemm_partial_kernel<<<g1, 256, 0, stream>>>(x, whi, wlo, part);
    gate_topk_kernel<<<NROWS / 4, 256, 0, stream>>>(part, bias, out);

    // diagnostic probe AFTER the real pipeline (production path untouched)
    gemm_probe_kernel<<<g1, 256, 0, stream>>>(x, whi, wlo, part2);
}